// Round 9
// baseline (209.156 us; speedup 1.0000x reference)
//
#include <hip/hip_runtime.h>

// Problem constants
#define CCH   640        // channels
#define WIN   19         // input spatial width
#define NWp   5          // pooled width
#define P     25         // NW*NW
#define BSn   100        // B*S
#define BSC   64000      // BSn*CCH slices per tensor
#define META_ELEMS 3200000
#define SLICE_F 361      // 19*19
#define WGRP_SL 4        // slices per group (5776 B, 16B-aligned)
#define WGRP_F  (WGRP_SL * SLICE_F)   // 1444 floats
#define WGRP_V4 361      // float4s per group
#define NWG_PER_TENSOR (BSC / WGRP_SL)   // 16000
#define NWG_TOTAL (2 * NWG_PER_TENSOR)   // 32000
#define POOL_BLOCKS 1600
#define POOL_WAVES  (POOL_BLOCKS * 4)    // 6400
#define GRP_PER_WAVE (NWG_TOTAL / POOL_WAVES)   // 5, exact

typedef float floatx4 __attribute__((ext_vector_type(4)));

__device__ __forceinline__ void nt_load_grp(const float* __restrict__ sup,
                                            const float* __restrict__ qry,
                                            int grp, int lane, floatx4* v) {
  const int which = (grp >= NWG_PER_TENSOR) ? 1 : 0;
  const int g = which ? grp - NWG_PER_TENSOR : grp;
  const float* __restrict__ src = (which ? qry : sup) + (size_t)g * WGRP_F;
#pragma unroll
  for (int i = 0; i < 6; ++i) {
    const int idx = i * 64 + lane;
    if (idx < WGRP_V4)
      v[i] = __builtin_nontemporal_load((const floatx4*)src + idx);
  }
}

// ---------------------------------------------------------------------------
// Kernel 1: adaptive avg pool, persistent waves with REGISTER double-buffer.
// Each wave owns one 5776B LDS region (occupancy unchanged vs single-buffer)
// and processes 5 groups: while pooling group k from LDS, group k+1's six
// nontemporal float4 loads are in flight into VGPRs. No barriers; compiler
// inserts within-wave vmcnt/lgkmcnt waits (DS ops are wave-program-ordered).
// ---------------------------------------------------------------------------
__global__ __launch_bounds__(256) void pool_kernel(
    const float* __restrict__ sup, const float* __restrict__ qry,
    float* __restrict__ out) {
  __shared__ __align__(16) float tile[4][WGRP_F];   // 23104 B, wave-private
  const int lane = threadIdx.x & 63;
  const int wave = threadIdx.x >> 6;
  const int wid = blockIdx.x * 4 + wave;            // [0, 6400)
  float* __restrict__ lt = &tile[wave][0];

  floatx4 v[6];
  nt_load_grp(sup, qry, wid, lane, v);              // prefetch group 0

#pragma unroll
  for (int k = 0; k < GRP_PER_WAVE; ++k) {
    const int grp = wid + k * POOL_WAVES;

    // Commit prefetched registers to this wave's LDS region.
#pragma unroll
    for (int i = 0; i < 6; ++i) {
      const int idx = i * 64 + lane;
      if (idx < WGRP_V4) *(floatx4*)(lt + idx * 4) = v[i];
    }
    // Issue next group's loads immediately (in flight during pooling).
    if (k + 1 < GRP_PER_WAVE)
      nt_load_grp(sup, qry, wid + (k + 1) * POOL_WAVES, lane, v);

    // Pool group k: 100 outputs per wave.
    const int which = (grp >= NWG_PER_TENSOR) ? 1 : 0;
    const int g = which ? grp - NWG_PER_TENSOR : grp;
    const int slice0 = g * WGRP_SL;
    for (int o = lane; o < WGRP_SL * P; o += 64) {
      const int s = o / P, p = o - s * P;
      const int i = p / NWp, j = p - i * NWp;
      const int r0 = (i * WIN) / NWp, r1 = ((i + 1) * WIN + NWp - 1) / NWp;
      const int c0 = (j * WIN) / NWp, c1 = ((j + 1) * WIN + NWp - 1) / NWp;
      const float* __restrict__ tb = lt + s * SLICE_F;
      float sum = 0.f;
      for (int r = r0; r < r1; ++r)
#pragma unroll
        for (int c = 0; c < 5; ++c) {               // max bin width is 5
          if (c0 + c < c1) sum += tb[r * WIN + c0 + c];
        }
      const float val = sum / (float)((r1 - r0) * (c1 - c0));
      const int rem = slice0 + s;
      const int bs = rem / CCH, cch = rem - bs * CCH;
      out[((size_t)bs * (2 * CCH) + which * CCH + cch) * P + p] = val;
    }
  }
}

// ---------------------------------------------------------------------------
// Kernel 2a: partial dots/norms per (bs, 128-channel chunk). 500 blocks.
// Transposed padded LDS layout [p][c] so dot loops use ds_read_b128.
// ---------------------------------------------------------------------------
#define CHUNK 128
#define ROWS  132                         // CHUNK + 4 pad
__global__ __launch_bounds__(640) void cos_part(
    const float* __restrict__ meta, float* __restrict__ dpart,
    float* __restrict__ spart, float* __restrict__ qpart) {
  __shared__ __align__(16) float ls[P * ROWS];
  __shared__ __align__(16) float lq[P * ROWS];
  const int t = threadIdx.x;
  const int blk = blockIdx.x;              // bs*5 + ch
  const int bs = blk / 5, ch = blk - bs * 5;
  const float* __restrict__ sb = meta + (size_t)bs * (2 * CCH * P) + ch * (CHUNK * P);
  const float* __restrict__ qb = sb + CCH * P;

  for (int idx = t; idx < CHUNK * P; idx += 640) {
    const int c = idx / P, p = idx - c * P;
    ls[p * ROWS + c] = sb[idx];
    lq[p * ROWS + c] = qb[idx];
  }
  __syncthreads();

  if (t < P * P) {
    const int p = t / P, q = t - p * P;
    const floatx4* __restrict__ ap = (const floatx4*)(ls + p * ROWS);
    const floatx4* __restrict__ bq = (const floatx4*)(lq + q * ROWS);
    floatx4 acc = {0.f, 0.f, 0.f, 0.f};
#pragma unroll 8
    for (int k = 0; k < CHUNK / 4; ++k) {
      const floatx4 a = ap[k], b = bq[k];
      acc.x = fmaf(a.x, b.x, acc.x);
      acc.y = fmaf(a.y, b.y, acc.y);
      acc.z = fmaf(a.z, b.z, acc.z);
      acc.w = fmaf(a.w, b.w, acc.w);
    }
    dpart[(size_t)blk * (P * P) + t] = (acc.x + acc.y) + (acc.z + acc.w);
  }
  if (t < P) {
    const floatx4* __restrict__ ap = (const floatx4*)(ls + t * ROWS);
    floatx4 acc = {0.f, 0.f, 0.f, 0.f};
#pragma unroll 8
    for (int k = 0; k < CHUNK / 4; ++k) {
      const floatx4 a = ap[k];
      acc.x = fmaf(a.x, a.x, acc.x);
      acc.y = fmaf(a.y, a.y, acc.y);
      acc.z = fmaf(a.z, a.z, acc.z);
      acc.w = fmaf(a.w, a.w, acc.w);
    }
    spart[blk * P + t] = (acc.x + acc.y) + (acc.z + acc.w);
  } else if (t >= 32 && t < 32 + P) {
    const int q = t - 32;
    const floatx4* __restrict__ bq = (const floatx4*)(lq + q * ROWS);
    floatx4 acc = {0.f, 0.f, 0.f, 0.f};
#pragma unroll 8
    for (int k = 0; k < CHUNK / 4; ++k) {
      const floatx4 b = bq[k];
      acc.x = fmaf(b.x, b.x, acc.x);
      acc.y = fmaf(b.y, b.y, acc.y);
      acc.z = fmaf(b.z, b.z, acc.z);
      acc.w = fmaf(b.w, b.w, acc.w);
    }
    qpart[blk * P + q] = (acc.x + acc.y) + (acc.z + acc.w);
  }
}

// ---------------------------------------------------------------------------
// Kernel 2b: reduce 5 partials, normalize, max over query positions.
// ---------------------------------------------------------------------------
__global__ __launch_bounds__(640) void cos_final(
    const float* __restrict__ dpart, const float* __restrict__ spart,
    const float* __restrict__ qpart, float* __restrict__ out) {
  __shared__ float sn[P], qn[P], simbuf[P * P];
  const int t = threadIdx.x, bs = blockIdx.x;
  if (t < P) {
    float a = 0.f;
#pragma unroll
    for (int ch = 0; ch < 5; ++ch) a += spart[(bs * 5 + ch) * P + t];
    sn[t] = sqrtf(a);
  } else if (t >= 32 && t < 32 + P) {
    const int q = t - 32;
    float a = 0.f;
#pragma unroll
    for (int ch = 0; ch < 5; ++ch) a += qpart[(bs * 5 + ch) * P + q];
    qn[q] = sqrtf(a);
  }
  __syncthreads();
  if (t < P * P) {
    const int p = t / P, q = t - p * P;
    float d = 0.f;
#pragma unroll
    for (int ch = 0; ch < 5; ++ch) d += dpart[(size_t)(bs * 5 + ch) * (P * P) + t];
    simbuf[t] = d / fmaxf(sn[p] * qn[q], 1e-8f);
  }
  __syncthreads();
  if (t < P) {
    float m = simbuf[t * P];
#pragma unroll
    for (int k = 1; k < P; ++k) m = fmaxf(m, simbuf[t * P + k]);
    out[META_ELEMS + bs * P + t] = m;
  }
}

extern "C" void kernel_launch(void* const* d_in, const int* in_sizes, int n_in,
                              void* d_out, int out_size, void* d_ws, size_t ws_size,
                              hipStream_t stream) {
  const float* sup = (const float*)d_in[0];
  const float* qry = (const float*)d_in[1];
  float* out = (float*)d_out;

  // Workspace (floats): dpart[500*625], spart[500*25], qpart[500*25]
  float* dpart = (float*)d_ws;
  float* spart = dpart + 500 * (P * P);
  float* qpart = spart + 500 * P;

  pool_kernel<<<POOL_BLOCKS, 256, 0, stream>>>(sup, qry, out);
  cos_part<<<BSn * 5, 640, 0, stream>>>(out, dpart, spart, qpart);
  cos_final<<<BSn, 640, 0, stream>>>(dpart, spart, qpart, out);
}

// Round 10
// 199.540 us; speedup vs baseline: 1.0482x; 1.0482x over previous
//
#include <hip/hip_runtime.h>

// Problem constants
#define CCH   640        // channels
#define WIN   19         // input spatial width
#define NWp   5          // pooled width
#define P     25         // NW*NW
#define BSn   100        // B*S
#define BSC   64000      // BSn*CCH slices per tensor
#define META_ELEMS 3200000
#define SLICE_F 361      // 19*19
#define WGRP_SL 4        // slices per group (5776 B, 16B-aligned)
#define WGRP_F  (WGRP_SL * SLICE_F)   // 1444 floats
#define WGRP_V4 361      // float4s per group
#define NWG_PER_TENSOR (BSC / WGRP_SL)   // 16000
#define POOL_BLOCKS 4000                 // 4 waves/block, 16000 waves
                                         // each wave: 1 support grp + 1 query grp

typedef float floatx4 __attribute__((ext_vector_type(4)));

__device__ __forceinline__ void nt_load_grp(const float* __restrict__ base,
                                            int g, int lane, floatx4* v) {
  const float* __restrict__ src = base + (size_t)g * WGRP_F;
#pragma unroll
  for (int i = 0; i < 6; ++i) {
    const int idx = i * 64 + lane;
    if (idx < WGRP_V4)
      v[i] = __builtin_nontemporal_load((const floatx4*)src + idx);
  }
}

// ---------------------------------------------------------------------------
// Kernel 1: adaptive avg pool. R8 structure (wave-autonomous, nontemporal
// float4 staging -> wave-private LDS -> pool -> store, no barriers) with one
// addition: each wave handles its support group THEN the same-index query
// group, issuing the query loads before pooling support — one HBM latency
// per wave is covered by compute, TLP stays at 4000 blocks (residency is
// LDS-capped at ~6 blocks/CU either way).
// ---------------------------------------------------------------------------
__global__ __launch_bounds__(256) void pool_kernel(
    const float* __restrict__ sup, const float* __restrict__ qry,
    float* __restrict__ out) {
  __shared__ __align__(16) float tile[4][WGRP_F];   // 23104 B, wave-private
  const int lane = threadIdx.x & 63;
  const int wave = threadIdx.x >> 6;
  const int wid = blockIdx.x * 4 + wave;            // [0, 16000) = group idx g
  float* __restrict__ lt = &tile[wave][0];

  floatx4 v[6];
  nt_load_grp(sup, wid, lane, v);                   // support group in flight

#pragma unroll
  for (int half = 0; half < 2; ++half) {
    // Commit the in-flight group's registers to this wave's LDS region.
#pragma unroll
    for (int i = 0; i < 6; ++i) {
      const int idx = i * 64 + lane;
      if (idx < WGRP_V4) *(floatx4*)(lt + idx * 4) = v[i];
    }
    // Kick off the query group's loads before pooling support.
    if (half == 0) nt_load_grp(qry, wid, lane, v);

    // Pool: 100 outputs per group.
    const int slice0 = wid * WGRP_SL;
    for (int o = lane; o < WGRP_SL * P; o += 64) {
      const int s = o / P, p = o - s * P;
      const int i = p / NWp, j = p - i * NWp;
      const int r0 = (i * WIN) / NWp, r1 = ((i + 1) * WIN + NWp - 1) / NWp;
      const int c0 = (j * WIN) / NWp, c1 = ((j + 1) * WIN + NWp - 1) / NWp;
      const float* __restrict__ tb = lt + s * SLICE_F;
      float sum = 0.f;
      for (int r = r0; r < r1; ++r)
#pragma unroll
        for (int c = 0; c < 5; ++c) {               // max bin width is 5
          if (c0 + c < c1) sum += tb[r * WIN + c0 + c];
        }
      const float val = sum / (float)((r1 - r0) * (c1 - c0));
      const int rem = slice0 + s;
      const int bs = rem / CCH, cch = rem - bs * CCH;
      out[((size_t)bs * (2 * CCH) + half * CCH + cch) * P + p] = val;
    }
  }
}

// ---------------------------------------------------------------------------
// Kernel 2a: partial dots/norms per (bs, 128-channel chunk). 500 blocks.
// Transposed padded LDS layout [p][c] so dot loops use ds_read_b128.
// ---------------------------------------------------------------------------
#define CHUNK 128
#define ROWS  132                         // CHUNK + 4 pad
__global__ __launch_bounds__(640) void cos_part(
    const float* __restrict__ meta, float* __restrict__ dpart,
    float* __restrict__ spart, float* __restrict__ qpart) {
  __shared__ __align__(16) float ls[P * ROWS];
  __shared__ __align__(16) float lq[P * ROWS];
  const int t = threadIdx.x;
  const int blk = blockIdx.x;              // bs*5 + ch
  const int bs = blk / 5, ch = blk - bs * 5;
  const float* __restrict__ sb = meta + (size_t)bs * (2 * CCH * P) + ch * (CHUNK * P);
  const float* __restrict__ qb = sb + CCH * P;

  for (int idx = t; idx < CHUNK * P; idx += 640) {
    const int c = idx / P, p = idx - c * P;
    ls[p * ROWS + c] = sb[idx];
    lq[p * ROWS + c] = qb[idx];
  }
  __syncthreads();

  if (t < P * P) {
    const int p = t / P, q = t - p * P;
    const floatx4* __restrict__ ap = (const floatx4*)(ls + p * ROWS);
    const floatx4* __restrict__ bq = (const floatx4*)(lq + q * ROWS);
    floatx4 acc = {0.f, 0.f, 0.f, 0.f};
#pragma unroll 8
    for (int k = 0; k < CHUNK / 4; ++k) {
      const floatx4 a = ap[k], b = bq[k];
      acc.x = fmaf(a.x, b.x, acc.x);
      acc.y = fmaf(a.y, b.y, acc.y);
      acc.z = fmaf(a.z, b.z, acc.z);
      acc.w = fmaf(a.w, b.w, acc.w);
    }
    dpart[(size_t)blk * (P * P) + t] = (acc.x + acc.y) + (acc.z + acc.w);
  }
  if (t < P) {
    const floatx4* __restrict__ ap = (const floatx4*)(ls + t * ROWS);
    floatx4 acc = {0.f, 0.f, 0.f, 0.f};
#pragma unroll 8
    for (int k = 0; k < CHUNK / 4; ++k) {
      const floatx4 a = ap[k];
      acc.x = fmaf(a.x, a.x, acc.x);
      acc.y = fmaf(a.y, a.y, acc.y);
      acc.z = fmaf(a.z, a.z, acc.z);
      acc.w = fmaf(a.w, a.w, acc.w);
    }
    spart[blk * P + t] = (acc.x + acc.y) + (acc.z + acc.w);
  } else if (t >= 32 && t < 32 + P) {
    const int q = t - 32;
    const floatx4* __restrict__ bq = (const floatx4*)(lq + q * ROWS);
    floatx4 acc = {0.f, 0.f, 0.f, 0.f};
#pragma unroll 8
    for (int k = 0; k < CHUNK / 4; ++k) {
      const floatx4 b = bq[k];
      acc.x = fmaf(b.x, b.x, acc.x);
      acc.y = fmaf(b.y, b.y, acc.y);
      acc.z = fmaf(b.z, b.z, acc.z);
      acc.w = fmaf(b.w, b.w, acc.w);
    }
    qpart[blk * P + q] = (acc.x + acc.y) + (acc.z + acc.w);
  }
}

// ---------------------------------------------------------------------------
// Kernel 2b: reduce 5 partials, normalize, max over query positions.
// ---------------------------------------------------------------------------
__global__ __launch_bounds__(640) void cos_final(
    const float* __restrict__ dpart, const float* __restrict__ spart,
    const float* __restrict__ qpart, float* __restrict__ out) {
  __shared__ float sn[P], qn[P], simbuf[P * P];
  const int t = threadIdx.x, bs = blockIdx.x;
  if (t < P) {
    float a = 0.f;
#pragma unroll
    for (int ch = 0; ch < 5; ++ch) a += spart[(bs * 5 + ch) * P + t];
    sn[t] = sqrtf(a);
  } else if (t >= 32 && t < 32 + P) {
    const int q = t - 32;
    float a = 0.f;
#pragma unroll
    for (int ch = 0; ch < 5; ++ch) a += qpart[(bs * 5 + ch) * P + q];
    qn[q] = sqrtf(a);
  }
  __syncthreads();
  if (t < P * P) {
    const int p = t / P, q = t - p * P;
    float d = 0.f;
#pragma unroll
    for (int ch = 0; ch < 5; ++ch) d += dpart[(size_t)(bs * 5 + ch) * (P * P) + t];
    simbuf[t] = d / fmaxf(sn[p] * qn[q], 1e-8f);
  }
  __syncthreads();
  if (t < P) {
    float m = simbuf[t * P];
#pragma unroll
    for (int k = 1; k < P; ++k) m = fmaxf(m, simbuf[t * P + k]);
    out[META_ELEMS + bs * P + t] = m;
  }
}

extern "C" void kernel_launch(void* const* d_in, const int* in_sizes, int n_in,
                              void* d_out, int out_size, void* d_ws, size_t ws_size,
                              hipStream_t stream) {
  const float* sup = (const float*)d_in[0];
  const float* qry = (const float*)d_in[1];
  float* out = (float*)d_out;

  // Workspace (floats): dpart[500*625], spart[500*25], qpart[500*25]
  float* dpart = (float*)d_ws;
  float* spart = dpart + 500 * (P * P);
  float* qpart = spart + 500 * P;

  pool_kernel<<<POOL_BLOCKS, 256, 0, stream>>>(sup, qry, out);
  cos_part<<<BSn * 5, 640, 0, stream>>>(out, dpart, spart, qpart);
  cos_final<<<BSn, 640, 0, stream>>>(dpart, spart, qpart, out);
}